// Round 7
// baseline (24.994 us; speedup 1.0000x reference)
//
#include <hip/hip_runtime.h>

#define BB 16
#define TT 2048
#define DD 768

typedef float f32x4 __attribute__((ext_vector_type(4)));

// ---------------------------------------------------------------------------
// Fused kernel, R7: one block of 512 threads (8 waves) per 32 output rows of
// one batch. Each block redundantly re-reads its batch's masks (L2-resident,
// 16 KB) and recomputes the block-wide prefix scan (shuffle-based, 4 elems
// per thread), selects the 32 source indices for its rows into LDS, then
// gathers those rows with inline PE and zero-fills padded rows.
// vs R6: block 256->512, rows/block 16->32 => per-CU redundant scan halves,
// occupancy unchanged (4 blocks/CU x 8 waves = 32 waves/CU).
// ---------------------------------------------------------------------------
__global__ void __launch_bounds__(512)
pm_fused_kernel(const int* __restrict__ nonvis,
                const int* __restrict__ pad,
                const float* __restrict__ wav,
                float* __restrict__ out_vis,
                float* __restrict__ out_mask,
                float* __restrict__ out_lens) {
    const int blk = blockIdx.x;            // 0..1023
    const int b = blk >> 6;                // blk / 64
    const int j0 = (blk & 63) << 5;        // 32 rows per block
    const int tid = threadIdx.x;           // 0..511
    const int base_t = tid * 4;
    const int lane = tid & 63;
    const int wid = tid >> 6;              // 0..7

    // ---- scan phase (redundant per block; masks are L2-resident) ----
    const int4 nva = reinterpret_cast<const int4*>(nonvis + b * TT)[tid];
    const int4 pda = reinterpret_cast<const int4*>(pad + b * TT)[tid];

    int keep[4];
    keep[0] = (nva.x == 0) && (pda.x == 0);
    keep[1] = (nva.y == 0) && (pda.y == 0);
    keep[2] = (nva.z == 0) && (pda.z == 0);
    keep[3] = (nva.w == 0) && (pda.w == 0);

    int cnt = keep[0] + keep[1] + keep[2] + keep[3];

    // wave-level inclusive scan (6 shuffle rounds)
    int x = cnt;
#pragma unroll
    for (int off = 1; off < 64; off <<= 1) {
        const int v = __shfl_up(x, off);
        if (lane >= off) x += v;
    }

    __shared__ int wtot[8];
    __shared__ int s_src[32];
    if (lane == 63) wtot[wid] = x;
    __syncthreads();

    int total = 0, wbase = 0;
#pragma unroll
    for (int w = 0; w < 8; ++w) {
        const int tw = wtot[w];
        total += tw;
        if (w < wid) wbase += tw;
    }

    // exclusive prefix of this thread's first element
    int p = wbase + x - cnt;

    // select the source t for output rows [j0, j0+32) into LDS
#pragma unroll
    for (int k = 0; k < 4; ++k) {
        if (keep[k]) {
            const int r = p - j0;
            if ((unsigned)r < 32u) s_src[r] = base_t + k;
            ++p;
        }
    }
    __syncthreads();

    // ---- small outputs ----
    if (tid < 32)
        out_mask[b * TT + j0 + tid] = (j0 + tid >= total) ? 1.0f : 0.0f;
    if ((blk & 63) == 0 && tid == 0)
        out_lens[b] = (float)total;

    // ---- hoisted per-lane PE factors (independent of output row) ----
    // d4 = lane + s*64; d = d4*4 + k; i = d (sin half) or d-384 (cos half)
    float inv[3][4];
    bool is_sin[3];
#pragma unroll
    for (int s = 0; s < 3; ++s) {
        const int d0 = (lane + s * 64) * 4;
        is_sin[s] = (d0 < DD / 2);
#pragma unroll
        for (int k = 0; k < 4; ++k) {
            const int d = d0 + k;
            const int i = is_sin[s] ? d : (d - DD / 2);
            // 10000^(-2i/D) = exp(-ln(10000)*2/D * i); ln(10000)*2/768
            inv[s][k] = __expf(-0.0239852613853510f * (float)i);
        }
    }

    // ---- gather phase: wave wid handles rows j0 + wid*4 .. +3 ----
#pragma unroll
    for (int q = 0; q < 4; ++q) {
        const int r = wid * 4 + q;
        const int j = j0 + r;
        f32x4* orow = reinterpret_cast<f32x4*>(out_vis + ((size_t)(b * TT + j)) * DD);

        if (j < total) {
            const int t = s_src[r];
            const f32x4* arow =
                reinterpret_cast<const f32x4*>(wav + ((size_t)(b * TT + t)) * DD);
            const float tf = (float)t;
#pragma unroll
            for (int s = 0; s < 3; ++s) {
                const int d4 = lane + s * 64;
                const f32x4 a = arow[d4];
                f32x4 v;
#pragma unroll
                for (int k = 0; k < 4; ++k) {
                    const float ang = tf * inv[s][k];
                    const float pe = is_sin[s] ? __sinf(ang) : __cosf(ang);
                    v[k] = a[k] + pe;
                }
                orow[d4] = v;
            }
        } else {
            const f32x4 z = {0.f, 0.f, 0.f, 0.f};
#pragma unroll
            for (int s = 0; s < 3; ++s)
                orow[lane + s * 64] = z;
        }
    }
}

extern "C" void kernel_launch(void* const* d_in, const int* in_sizes, int n_in,
                              void* d_out, int out_size, void* d_ws, size_t ws_size,
                              hipStream_t stream) {
    const float* wav   = (const float*)d_in[0];
    const int* nonvis  = (const int*)d_in[1];
    const int* pad     = (const int*)d_in[2];

    float* out       = (float*)d_out;
    float* out_vis   = out;                              // B*T*D
    float* out_mask  = out + (size_t)BB * TT * DD;       // B*T
    float* out_lens  = out_mask + BB * TT;               // B

    pm_fused_kernel<<<BB * TT / 32, 512, 0, stream>>>(nonvis, pad, wav,
                                                      out_vis, out_mask, out_lens);
}

// Round 8
// 24.706 us; speedup vs baseline: 1.0116x; 1.0116x over previous
//
#include <hip/hip_runtime.h>

#define BB 16
#define TT 2048
#define DD 768

typedef float f32x4 __attribute__((ext_vector_type(4)));

// ---------------------------------------------------------------------------
// Fused kernel, R8: one block (256 thr, 4 waves) per 16 output rows of one
// batch. Ballot+popcount scan (no shuffle dependency chain) + MLP-prefetched
// gather: all 12 row-loads (4 rows x 3 float4/lane) issued before any
// compute/store, so vmcnt partial waits overlap latency across rows.
// ---------------------------------------------------------------------------
__global__ void __launch_bounds__(256)
pm_fused_kernel(const int* __restrict__ nonvis,
                const int* __restrict__ pad,
                const float* __restrict__ wav,
                float* __restrict__ out_vis,
                float* __restrict__ out_mask,
                float* __restrict__ out_lens) {
    const int blk = blockIdx.x;            // 0..2047
    const int b = blk >> 7;                // blk / 128
    const int j0 = (blk & 127) << 4;       // 16 rows per block
    const int tid = threadIdx.x;           // 0..255
    const int base_t = tid * 8;
    const int lane = tid & 63;
    const int wid = tid >> 6;              // 0..3

    // ---- scan phase: ballot + popcount (masks are L2-resident) ----
    const int4* nv4 = reinterpret_cast<const int4*>(nonvis + b * TT) + tid * 2;
    const int4* pd4 = reinterpret_cast<const int4*>(pad + b * TT) + tid * 2;
    const int4 nva = nv4[0], nvb = nv4[1];
    const int4 pda = pd4[0], pdb = pd4[1];

    int keep[8];
    keep[0] = (nva.x == 0) && (pda.x == 0);
    keep[1] = (nva.y == 0) && (pda.y == 0);
    keep[2] = (nva.z == 0) && (pda.z == 0);
    keep[3] = (nva.w == 0) && (pda.w == 0);
    keep[4] = (nvb.x == 0) && (pdb.x == 0);
    keep[5] = (nvb.y == 0) && (pdb.y == 0);
    keep[6] = (nvb.z == 0) && (pdb.z == 0);
    keep[7] = (nvb.w == 0) && (pdb.w == 0);

    const unsigned long long lt = (1ull << lane) - 1ull;
    int base = 0;      // kept elements in earlier lanes of this wave
    int wtotal = 0;    // kept elements in this wave
#pragma unroll
    for (int k = 0; k < 8; ++k) {
        const unsigned long long mk = __ballot(keep[k]);
        base += __popcll(mk & lt);
        wtotal += __popcll(mk);
    }

    __shared__ int wtot[4];
    __shared__ int s_src[16];
    if (lane == 0) wtot[wid] = wtotal;
    __syncthreads();

    const int t0 = wtot[0], t1 = wtot[1], t2 = wtot[2], t3 = wtot[3];
    const int total = t0 + t1 + t2 + t3;
    int wbase = 0;
    if (wid > 0) wbase += t0;
    if (wid > 1) wbase += t1;
    if (wid > 2) wbase += t2;

    // exclusive prefix of this thread's first element
    int p = wbase + base;

    // select the source t for output rows [j0, j0+16) into LDS
#pragma unroll
    for (int k = 0; k < 8; ++k) {
        if (keep[k]) {
            const int r = p - j0;
            if ((unsigned)r < 16u) s_src[r] = base_t + k;
            ++p;
        }
    }
    __syncthreads();

    // ---- small outputs ----
    if (tid < 16)
        out_mask[b * TT + j0 + tid] = (j0 + tid >= total) ? 1.0f : 0.0f;
    if ((blk & 127) == 0 && tid == 0)
        out_lens[b] = (float)total;

    // ---- hoisted per-lane PE factors ----
    float inv[3][4];
    bool is_sin[3];
#pragma unroll
    for (int s = 0; s < 3; ++s) {
        const int d0 = (lane + s * 64) * 4;
        is_sin[s] = (d0 < DD / 2);
#pragma unroll
        for (int k = 0; k < 4; ++k) {
            const int d = d0 + k;
            const int i = is_sin[s] ? d : (d - DD / 2);
            // 10000^(-2i/D) = exp(-ln(10000)*2/D * i); ln(10000)*2/768
            inv[s][k] = __expf(-0.0239852613853510f * (float)i);
        }
    }

    // ---- gather phase: wave wid owns rows j0 + wid*4 .. +3 ----
    const int rbase = wid * 4;
    int nv = total - (j0 + rbase);         // rows with j < total (wave-uniform)
    nv = nv < 0 ? 0 : (nv > 4 ? 4 : nv);

    // issue ALL loads first (12 float4s in flight per lane)
    f32x4 a[4][3];
    float tf[4];
#pragma unroll
    for (int q = 0; q < 4; ++q) {
        if (q < nv) {
            const int t = s_src[rbase + q];
            tf[q] = (float)t;
            const f32x4* arow =
                reinterpret_cast<const f32x4*>(wav + ((size_t)(b * TT + t)) * DD);
#pragma unroll
            for (int s = 0; s < 3; ++s)
                a[q][s] = arow[lane + s * 64];
        }
    }

    // compute + store per row
#pragma unroll
    for (int q = 0; q < 4; ++q) {
        const int j = j0 + rbase + q;
        f32x4* orow = reinterpret_cast<f32x4*>(out_vis + ((size_t)(b * TT + j)) * DD);
        if (q < nv) {
#pragma unroll
            for (int s = 0; s < 3; ++s) {
                f32x4 v;
#pragma unroll
                for (int k = 0; k < 4; ++k) {
                    const float ang = tf[q] * inv[s][k];
                    const float pe = is_sin[s] ? __sinf(ang) : __cosf(ang);
                    v[k] = a[q][s][k] + pe;
                }
                orow[lane + s * 64] = v;
            }
        } else {
            const f32x4 z = {0.f, 0.f, 0.f, 0.f};
#pragma unroll
            for (int s = 0; s < 3; ++s)
                orow[lane + s * 64] = z;
        }
    }
}

extern "C" void kernel_launch(void* const* d_in, const int* in_sizes, int n_in,
                              void* d_out, int out_size, void* d_ws, size_t ws_size,
                              hipStream_t stream) {
    const float* wav   = (const float*)d_in[0];
    const int* nonvis  = (const int*)d_in[1];
    const int* pad     = (const int*)d_in[2];

    float* out       = (float*)d_out;
    float* out_vis   = out;                              // B*T*D
    float* out_mask  = out + (size_t)BB * TT * DD;       // B*T
    float* out_lens  = out_mask + BB * TT;               // B

    pm_fused_kernel<<<BB * TT / 16, 256, 0, stream>>>(nonvis, pad, wav,
                                                      out_vis, out_mask, out_lens);
}